// Round 2
// 1009.817 us; speedup vs baseline: 1.0106x; 1.0106x over previous
//
#include <hip/hip_runtime.h>

// Problem constants: B=128, S=2048, H=512.
//   d_in: 0 query[128,1,512] f32, 1 keys[128,2048,512] f32, 2 Wa[512,512], 3 ba[512],
//         4 Ua[512,512], 5 bu[512], 6 Va[1,512], 7 bv[1]
//   d_out: context[128,1,512] (65536 f32) then weights[128,1,2048] (262144 f32)
//
// Pipeline (all scratch lives inside d_out regions; ws unused):
//   wqb  = query.Wa^T + ba + bu            -> stored in d_out[0:65536] (context region)
//   scores[b,s] = sum_o Va[o]*tanh(wqb[b,o] + keys[b,s,:].Ua[o,:])   (bv dropped: softmax-invariant)
//        -> atomicAdd into d_out[65536:] (weights region), memset to 0 first
//   softmax in place over S; same kernel zeroes context region
//   context = weights . keys  -> atomicAdd into d_out[0:65536]

#define BM 128
#define BN 128
#define BK 32
#define LDK 40  // padded LDS inner dim in shorts (80B rows: 16B-aligned, conflict-friendly)

typedef __attribute__((ext_vector_type(8))) short bf16x8;
typedef __attribute__((ext_vector_type(4))) float f32x4;

// Pack two f32 -> two bf16 (round-to-nearest) in 3 VALU ops:
// two v_add_u32 + one v_perm_b32 (bytes [3:2] of each rounded word).
// RN (half-up) vs RNE differs only on exact ties -> same accuracy class.
static __device__ inline unsigned pkbf(float lo, float hi) {
  unsigned a = __float_as_uint(lo) + 0x8000u;
  unsigned b = __float_as_uint(hi) + 0x8000u;
  return __builtin_amdgcn_perm(b, a, 0x07060302u);  // dst = {b[31:16], a[31:16]}
}

static __device__ inline void store8(short* dst, float4 a, float4 b) {
  union { bf16x8 v; unsigned u[4]; } w;
  w.u[0] = pkbf(a.x, a.y);
  w.u[1] = pkbf(a.z, a.w);
  w.u[2] = pkbf(b.x, b.y);
  w.u[3] = pkbf(b.z, b.w);
  *(bf16x8*)dst = w.v;
}

// ---------------- K1: wq = query.Wa^T + ba + bu -> wqb [128][512] ----------------
__global__ __launch_bounds__(512) void wq_kernel(const float* __restrict__ query,
                                                 const float* __restrict__ Wa,
                                                 const float* __restrict__ ba,
                                                 const float* __restrict__ bu,
                                                 float* __restrict__ wqb) {
  const int b = blockIdx.x;
  const int o = threadIdx.x;
  __shared__ float qs[512];
  qs[o] = query[(b << 9) + o];
  __syncthreads();
  const float4* w4 = (const float4*)(Wa + (size_t)o * 512);
  float acc = 0.f;
#pragma unroll 4
  for (int h = 0; h < 128; ++h) {
    float4 w = w4[h];
    acc += w.x * qs[4 * h] + w.y * qs[4 * h + 1] + w.z * qs[4 * h + 2] + w.w * qs[4 * h + 3];
  }
  wqb[(b << 9) + o] = acc + ba[o] + bu[o];
}

// ---------------- K2: fused GEMM + tanh + Va-dot -> partial scores ----------------
__global__ __launch_bounds__(256) void score_gemm(const float* __restrict__ keys,
                                                  const float* __restrict__ Ua,
                                                  const float* __restrict__ wqb,
                                                  const float* __restrict__ Va,
                                                  float* __restrict__ scores) {
  __shared__ short As[BM][LDK];
  __shared__ short Bs[BN][LDK];

  // Bijective XCD swizzle (nwg = 8192 = 8 * 1024): dispatch slot bid lands on
  // XCD bid%8; give each XCD a contiguous chunk of 1024 logical blocks so the
  // 4 sibling n-tiles of one keys m-tile hit the SAME L2 (kills the 2.1x
  // keys over-fetch seen in FETCH_SIZE).
  const int bid = blockIdx.x;
  const int lid = (bid & 7) * 1024 + (bid >> 3);
  const int n0 = (lid & 3) * BN;   // 4 column blocks (N=512), fastest in logical order
  const int m0 = (lid >> 2) * BM;  // 2048 row blocks (M=262144)
  const int b = m0 >> 11;          // 2048 rows per batch; 128 | 2048 so one b per block

  const int tid = threadIdx.x;
  const int lane = tid & 63;
  const int wave = tid >> 6;
  const int wm = (wave >> 1) * 64;
  const int wn = (wave & 1) * 64;
  const int mlane = lane & 15;
  const int quad = lane >> 4;

  const int sr = tid >> 2;        // staging row 0..63
  const int sc = (tid & 3) * 8;   // staging col {0,8,16,24}

  f32x4 zero = {0.f, 0.f, 0.f, 0.f};
  f32x4 acc[4][4];
#pragma unroll
  for (int i = 0; i < 4; ++i)
#pragma unroll
    for (int j = 0; j < 4; ++j) acc[i][j] = zero;

  for (int k0 = 0; k0 < 512; k0 += BK) {
    __syncthreads();
#pragma unroll
    for (int it = 0; it < 2; ++it) {
      const int row = sr + it * 64;
      const float* pa = keys + (size_t)(m0 + row) * 512 + k0 + sc;
      const float* pb = Ua + (size_t)(n0 + row) * 512 + k0 + sc;
      float4 a0 = *(const float4*)pa;
      float4 a1 = *(const float4*)(pa + 4);
      float4 b0 = *(const float4*)pb;
      float4 b1 = *(const float4*)(pb + 4);
      store8(&As[row][sc], a0, a1);
      store8(&Bs[row][sc], b0, b1);
    }
    __syncthreads();

    bf16x8 af[4], bfr[4];
#pragma unroll
    for (int i = 0; i < 4; ++i) af[i] = *(const bf16x8*)&As[wm + i * 16 + mlane][quad * 8];
#pragma unroll
    for (int j = 0; j < 4; ++j) bfr[j] = *(const bf16x8*)&Bs[wn + j * 16 + mlane][quad * 8];
#pragma unroll
    for (int i = 0; i < 4; ++i)
#pragma unroll
      for (int j = 0; j < 4; ++j)
        acc[i][j] = __builtin_amdgcn_mfma_f32_16x16x32_bf16(af[i], bfr[j], acc[i][j], 0, 0, 0);
  }

  // Epilogue: t = tanh(acc + wqb[b,n]); partial score = sum_n Va[n]*t
  // C/D layout (verified m89/m91): col = lane&15, row = quad*4 + reg
  float wqv[4], vav[4];
#pragma unroll
  for (int j = 0; j < 4; ++j) {
    const int n = n0 + wn + j * 16 + mlane;
    wqv[j] = wqb[(b << 9) + n];
    vav[j] = Va[n];
  }
  float rs[4][4] = {};
#pragma unroll
  for (int j = 0; j < 4; ++j)
#pragma unroll
    for (int i = 0; i < 4; ++i)
#pragma unroll
      for (int r = 0; r < 4; ++r) {
        const float v = acc[i][j][r] + wqv[j];
        // tanh(v) = 1 - 2/(e^{2v}+1); robust at +-inf, err ~1e-6
        const float e = __expf(2.0f * v);
        const float t = 1.0f - 2.0f * __builtin_amdgcn_rcpf(e + 1.0f);
        rs[i][r] += vav[j] * t;
      }
#pragma unroll
  for (int i = 0; i < 4; ++i)
#pragma unroll
    for (int r = 0; r < 4; ++r) {
      float v = rs[i][r];
      v += __shfl_xor(v, 1);
      v += __shfl_xor(v, 2);
      v += __shfl_xor(v, 4);
      v += __shfl_xor(v, 8);
      if (mlane == 0) {
        const int m = m0 + wm + i * 16 + quad * 4 + r;
        atomicAdd(&scores[m], v);
      }
    }
}

// ---------------- K3: softmax over S (in place) + zero context region ----------------
__global__ __launch_bounds__(256) void softmax_kernel(float* __restrict__ sw,
                                                      float* __restrict__ context) {
  const int b = blockIdx.x;
  const int t = threadIdx.x;
  // zero context for K4's atomics (wqb no longer needed)
  context[(b << 9) + t] = 0.f;
  context[(b << 9) + 256 + t] = 0.f;

  float* row = sw + (size_t)(b << 11);
  float4 x0 = *(float4*)(row + t * 8);
  float4 x1 = *(float4*)(row + t * 8 + 4);

  float mx = fmaxf(fmaxf(fmaxf(x0.x, x0.y), fmaxf(x0.z, x0.w)),
                   fmaxf(fmaxf(x1.x, x1.y), fmaxf(x1.z, x1.w)));
#pragma unroll
  for (int d = 1; d < 64; d <<= 1) mx = fmaxf(mx, __shfl_xor(mx, d));

  __shared__ float smax[4], ssum[4];
  const int wave = t >> 6, lane = t & 63;
  if (lane == 0) smax[wave] = mx;
  __syncthreads();
  mx = fmaxf(fmaxf(smax[0], smax[1]), fmaxf(smax[2], smax[3]));

  float e[8];
  e[0] = __expf(x0.x - mx); e[1] = __expf(x0.y - mx);
  e[2] = __expf(x0.z - mx); e[3] = __expf(x0.w - mx);
  e[4] = __expf(x1.x - mx); e[5] = __expf(x1.y - mx);
  e[6] = __expf(x1.z - mx); e[7] = __expf(x1.w - mx);
  float s = e[0] + e[1] + e[2] + e[3] + e[4] + e[5] + e[6] + e[7];
#pragma unroll
  for (int d = 1; d < 64; d <<= 1) s += __shfl_xor(s, d);
  if (lane == 0) ssum[wave] = s;
  __syncthreads();
  s = ssum[0] + ssum[1] + ssum[2] + ssum[3];
  const float inv = 1.0f / s;

  float4 y0, y1;
  y0.x = e[0] * inv; y0.y = e[1] * inv; y0.z = e[2] * inv; y0.w = e[3] * inv;
  y1.x = e[4] * inv; y1.y = e[5] * inv; y1.z = e[6] * inv; y1.w = e[7] * inv;
  *(float4*)(row + t * 8) = y0;
  *(float4*)(row + t * 8 + 4) = y1;
}

// ---------------- K4: context = weights . keys ----------------
// 2048 blocks (16 s-chunks of 128 per batch) -> 8 blocks/CU, 32 waves/CU.
// unroll-4 keeps ~12 loads in flight per thread: latency-hiding for the
// 512 MB keys stream (was 2 blocks/CU, dependent loop -> ~0.9 TB/s).
__global__ __launch_bounds__(256) void context_kernel(const float* __restrict__ keys,
                                                      const float* __restrict__ weights,
                                                      float* __restrict__ context) {
  const int b = blockIdx.x >> 4;
  const int chunk = blockIdx.x & 15;
  const int t = threadIdx.x;
  const int hg = t & 63;   // 64 h-groups of 8
  const int sl = t >> 6;   // 4 s-lanes (one wave each)

  float acc[8] = {0.f, 0.f, 0.f, 0.f, 0.f, 0.f, 0.f, 0.f};
  const float* wrow = weights + (size_t)(b << 11) + (chunk << 7);
  const float* kbase = keys + ((size_t)(b << 11) + (chunk << 7)) * 512 + hg * 8;
#pragma unroll 4
  for (int s = sl; s < 128; s += 4) {
    const float w = wrow[s];
    const float* kp = kbase + (size_t)s * 512;
    float4 k0 = *(const float4*)kp;
    float4 k1 = *(const float4*)(kp + 4);
    acc[0] += w * k0.x; acc[1] += w * k0.y; acc[2] += w * k0.z; acc[3] += w * k0.w;
    acc[4] += w * k1.x; acc[5] += w * k1.y; acc[6] += w * k1.z; acc[7] += w * k1.w;
  }
  __shared__ float red[4][512];
  float4 r0, r1;
  r0.x = acc[0]; r0.y = acc[1]; r0.z = acc[2]; r0.w = acc[3];
  r1.x = acc[4]; r1.y = acc[5]; r1.z = acc[6]; r1.w = acc[7];
  *(float4*)&red[sl][hg * 8] = r0;
  *(float4*)&red[sl][hg * 8 + 4] = r1;
  __syncthreads();
#pragma unroll
  for (int hh = 0; hh < 2; ++hh) {
    const int h = t + hh * 256;
    const float v = red[0][h] + red[1][h] + red[2][h] + red[3][h];
    atomicAdd(&context[(b << 9) + h], v);
  }
}

extern "C" void kernel_launch(void* const* d_in, const int* in_sizes, int n_in,
                              void* d_out, int out_size, void* d_ws, size_t ws_size,
                              hipStream_t stream) {
  const float* query = (const float*)d_in[0];
  const float* keys  = (const float*)d_in[1];
  const float* Wa    = (const float*)d_in[2];
  const float* ba    = (const float*)d_in[3];
  const float* Ua    = (const float*)d_in[4];
  const float* bu    = (const float*)d_in[5];
  const float* Va    = (const float*)d_in[6];
  // d_in[7] = bv: dropped (constant shift is softmax-invariant; scores are not an output)

  float* out = (float*)d_out;
  float* context = out;            // [128*512]
  float* weights = out + 65536;    // [128*2048]; doubles as scores scratch
  float* wqb = context;            // wq+ba+bu scratch; overwritten after score_gemm

  // zero scores for atomic accumulation
  hipMemsetAsync(weights, 0, (size_t)262144 * sizeof(float), stream);

  wq_kernel<<<dim3(128), dim3(512), 0, stream>>>(query, Wa, ba, bu, wqb);

  score_gemm<<<dim3(8192), dim3(256), 0, stream>>>(keys, Ua, wqb, Va, weights);

  softmax_kernel<<<dim3(128), dim3(256), 0, stream>>>(weights, context);

  context_kernel<<<dim3(2048), dim3(256), 0, stream>>>(keys, weights, context);
}